// Round 1
// baseline (450.672 us; speedup 1.0000x reference)
//
#include <hip/hip_runtime.h>
#include <hip/hip_bf16.h>
#include <math.h>

#define NH 16
#define HD 64
#define NWL 16

// ---------------------------------------------------------------------------
// GEMM: C[s][f] = sum_e X[s][e]*W[e][f] + bias[f]   (1024x1024x1024, fp32)
// 128x128 tiles, BK=16, 256 threads, 8x8 per thread.
// MODE 0: plain out[s*1024+f]   MODE 1: head-split out[h][s][d], h=f>>6,d=f&63
// blockIdx.z selects (W,bias,out) set so QKV runs as one launch.
// ---------------------------------------------------------------------------
template<int MODE>
__global__ __launch_bounds__(256)
void gemm_xw(const float* __restrict__ X,
             const float* __restrict__ Wa, const float* __restrict__ Wb2, const float* __restrict__ Wc,
             const float* __restrict__ Ba, const float* __restrict__ Bb, const float* __restrict__ Bc,
             float* __restrict__ Oa, float* __restrict__ Ob, float* __restrict__ Oc)
{
    const float* W = Wa; const float* bias = Ba; float* out = Oa;
    if (blockIdx.z == 1) { W = Wb2; bias = Bb; out = Ob; }
    if (blockIdx.z == 2) { W = Wc;  bias = Bc; out = Oc; }

    __shared__ float XT[16][132];   // X tile transposed [e][s]
    __shared__ float Ws[16][132];   // W tile [e][f]

    const int t = threadIdx.x;
    const int sbase = blockIdx.y * 128;
    const int fbase = blockIdx.x * 128;
    const int tr = t >> 4;
    const int tc = t & 15;
    const int r0 = tr * 8;
    const int c0 = tc * 8;

    float acc[8][8];
#pragma unroll
    for (int i = 0; i < 8; ++i)
#pragma unroll
        for (int j = 0; j < 8; ++j) acc[i][j] = 0.f;

    for (int kb = 0; kb < 1024; kb += 16) {
#pragma unroll
        for (int ii = 0; ii < 2; ++ii) {
            int idx = t + ii * 256;
            int row = idx >> 2;
            int e0 = (idx & 3) * 4;
            float4 v = *(const float4*)&X[(size_t)(sbase + row) * 1024 + kb + e0];
            XT[e0 + 0][row] = v.x;
            XT[e0 + 1][row] = v.y;
            XT[e0 + 2][row] = v.z;
            XT[e0 + 3][row] = v.w;
        }
#pragma unroll
        for (int ii = 0; ii < 2; ++ii) {
            int idx = t + ii * 256;
            int e = idx >> 5;
            int f0 = (idx & 31) * 4;
            *(float4*)&Ws[e][f0] = *(const float4*)&W[(size_t)(kb + e) * 1024 + fbase + f0];
        }
        __syncthreads();
#pragma unroll
        for (int k = 0; k < 16; ++k) {
            float a[8], b[8];
            *(float4*)&a[0] = *(const float4*)&XT[k][r0];
            *(float4*)&a[4] = *(const float4*)&XT[k][r0 + 4];
            *(float4*)&b[0] = *(const float4*)&Ws[k][c0];
            *(float4*)&b[4] = *(const float4*)&Ws[k][c0 + 4];
#pragma unroll
            for (int i = 0; i < 8; ++i)
#pragma unroll
                for (int j = 0; j < 8; ++j)
                    acc[i][j] = fmaf(a[i], b[j], acc[i][j]);
        }
        __syncthreads();
    }

#pragma unroll
    for (int i = 0; i < 8; ++i) {
        const int s = sbase + r0 + i;
#pragma unroll
        for (int j = 0; j < 8; ++j) acc[i][j] += bias[fbase + c0 + j];
        if (MODE == 0) {
            *(float4*)&out[(size_t)s * 1024 + fbase + c0]     = *(float4*)&acc[i][0];
            *(float4*)&out[(size_t)s * 1024 + fbase + c0 + 4] = *(float4*)&acc[i][4];
        } else {
            const int f = fbase + c0;          // 8 cols stay inside one head (8|64)
            const int h = f >> 6;
            const int d = f & 63;
            float* dst = out + ((size_t)h << 16) + ((size_t)s << 6) + d;
            *(float4*)&dst[0] = *(float4*)&acc[i][0];
            *(float4*)&dst[4] = *(float4*)&acc[i][4];
        }
    }
}

// ---------------------------------------------------------------------------
// Pass 1: per (head, row, wl) softmax denominators -> combined weight
//   wgt[h][q][wl] = iw[wl] / (16 * sum_k exp(c[wl]*S[q][k]))
// One block = (head, 64 q rows). S chunk recomputed by a 64x64 fp32 tile GEMM.
// No rowmax needed: |c*s| <= ~2.5 (bounded inputs), softmax shift-invariant.
// ---------------------------------------------------------------------------
__global__ __launch_bounds__(256)
void denom_k(const float* __restrict__ Qb, const float* __restrict__ Kb,
             const float* __restrict__ pm, const float* __restrict__ iw,
             float* __restrict__ wgt)
{
    const int h = blockIdx.y;
    const int qbase = blockIdx.x * 64;
    const int t = threadIdx.x;
    const int tr = t >> 4;     // 0..15 -> 4 rows each
    const int tc = t & 15;     // 0..15 -> 4 k each

    __shared__ float QT[64][68];   // Q tile transposed [d][row]
    __shared__ float KT[64][68];   // K chunk transposed [d][k]
    __shared__ float ccs[16];

    const float* Qh = Qb + ((size_t)h << 16);
    const float* Kh = Kb + ((size_t)h << 16);

    if (t < 16) { float m = cosf(pm[t * NH + h]); ccs[t] = m * m * 0.125f; }
    {
        const int rr = t >> 2;
        const int d0 = (t & 3) * 16;
#pragma unroll
        for (int j = 0; j < 4; ++j) {
            float4 v = *(const float4*)&Qh[(size_t)(qbase + rr) * 64 + d0 + j * 4];
            QT[d0 + j * 4 + 0][rr] = v.x;
            QT[d0 + j * 4 + 1][rr] = v.y;
            QT[d0 + j * 4 + 2][rr] = v.z;
            QT[d0 + j * 4 + 3][rr] = v.w;
        }
    }
    __syncthreads();

    float cl[16];
#pragma unroll
    for (int w = 0; w < NWL; ++w) cl[w] = ccs[w];

    float den[4][16];
#pragma unroll
    for (int i = 0; i < 4; ++i)
#pragma unroll
        for (int w = 0; w < NWL; ++w) den[i][w] = 0.f;

    for (int kb = 0; kb < 1024; kb += 64) {
        {
            const int kk = t >> 2;
            const int d0 = (t & 3) * 16;
#pragma unroll
            for (int j = 0; j < 4; ++j) {
                float4 v = *(const float4*)&Kh[(size_t)(kb + kk) * 64 + d0 + j * 4];
                KT[d0 + j * 4 + 0][kk] = v.x;
                KT[d0 + j * 4 + 1][kk] = v.y;
                KT[d0 + j * 4 + 2][kk] = v.z;
                KT[d0 + j * 4 + 3][kk] = v.w;
            }
        }
        __syncthreads();

        float s[4][4];
#pragma unroll
        for (int i = 0; i < 4; ++i)
#pragma unroll
            for (int j = 0; j < 4; ++j) s[i][j] = 0.f;
#pragma unroll 4
        for (int d = 0; d < 64; ++d) {
            float a[4], b[4];
            *(float4*)&a[0] = *(const float4*)&QT[d][tr * 4];
            *(float4*)&b[0] = *(const float4*)&KT[d][tc * 4];
#pragma unroll
            for (int i = 0; i < 4; ++i)
#pragma unroll
                for (int j = 0; j < 4; ++j)
                    s[i][j] = fmaf(a[i], b[j], s[i][j]);
        }
#pragma unroll
        for (int i = 0; i < 4; ++i)
#pragma unroll
            for (int j = 0; j < 4; ++j)
#pragma unroll
                for (int w = 0; w < NWL; ++w)
                    den[i][w] += __expf(cl[w] * s[i][j]);
        __syncthreads();
    }

    // reduce the 16 k-owning lanes of each row (lane bits [3:0] == tc)
#pragma unroll
    for (int off = 1; off < 16; off <<= 1)
#pragma unroll
        for (int i = 0; i < 4; ++i)
#pragma unroll
            for (int w = 0; w < NWL; ++w)
                den[i][w] += __shfl_xor(den[i][w], off, 64);

    if (tc == 0) {
#pragma unroll
        for (int i = 0; i < 4; ++i) {
            const int q = qbase + tr * 4 + i;
#pragma unroll
            for (int w = 0; w < NWL; ++w)
                wgt[(((size_t)h << 10) + q) * NWL + w] = iw[w] / (den[i][w] * 16.0f);
        }
    }
}

// ---------------------------------------------------------------------------
// Pass 2: fused S -> P_sum -> P_sum @ V, writing comb[s][h*64+d].
// P chunk reuses the KT LDS buffer (saves 17KB -> 52KB total static LDS).
// ---------------------------------------------------------------------------
__global__ __launch_bounds__(256)
void pv_k(const float* __restrict__ Qb, const float* __restrict__ Kb,
          const float* __restrict__ Vb, const float* __restrict__ pm,
          const float* __restrict__ wgt, float* __restrict__ comb)
{
    const int h = blockIdx.y;
    const int qbase = blockIdx.x * 64;
    const int t = threadIdx.x;
    const int tr = t >> 4;
    const int tc = t & 15;

    __shared__ float QT[64][68];
    __shared__ float KP[64][68];   // K^T chunk, then reused as P chunk [row][k]
    __shared__ float Vs[64][68];   // V chunk [k][d]
    __shared__ float ccs[16];

    const float* Qh = Qb + ((size_t)h << 16);
    const float* Kh = Kb + ((size_t)h << 16);
    const float* Vh = Vb + ((size_t)h << 16);

    if (t < 16) { float m = cosf(pm[t * NH + h]); ccs[t] = m * m * 0.125f; }
    {
        const int rr = t >> 2;
        const int d0 = (t & 3) * 16;
#pragma unroll
        for (int j = 0; j < 4; ++j) {
            float4 v = *(const float4*)&Qh[(size_t)(qbase + rr) * 64 + d0 + j * 4];
            QT[d0 + j * 4 + 0][rr] = v.x;
            QT[d0 + j * 4 + 1][rr] = v.y;
            QT[d0 + j * 4 + 2][rr] = v.z;
            QT[d0 + j * 4 + 3][rr] = v.w;
        }
    }
    __syncthreads();

    float cl[16];
#pragma unroll
    for (int w = 0; w < NWL; ++w) cl[w] = ccs[w];

    float wreg[4][16];
#pragma unroll
    for (int i = 0; i < 4; ++i) {
        const int q = qbase + tr * 4 + i;
#pragma unroll
        for (int w = 0; w < NWL; ++w)
            wreg[i][w] = wgt[(((size_t)h << 10) + q) * NWL + w];
    }

    float outA[4][4];
#pragma unroll
    for (int i = 0; i < 4; ++i)
#pragma unroll
        for (int j = 0; j < 4; ++j) outA[i][j] = 0.f;

    for (int kb = 0; kb < 1024; kb += 64) {
        {
            const int kk = t >> 2;
            const int d0 = (t & 3) * 16;
#pragma unroll
            for (int j = 0; j < 4; ++j) {
                float4 v = *(const float4*)&Kh[(size_t)(kb + kk) * 64 + d0 + j * 4];
                KP[d0 + j * 4 + 0][kk] = v.x;
                KP[d0 + j * 4 + 1][kk] = v.y;
                KP[d0 + j * 4 + 2][kk] = v.z;
                KP[d0 + j * 4 + 3][kk] = v.w;
                *(float4*)&Vs[kk][d0 + j * 4] =
                    *(const float4*)&Vh[(size_t)(kb + kk) * 64 + d0 + j * 4];
            }
        }
        __syncthreads();

        float s[4][4];
#pragma unroll
        for (int i = 0; i < 4; ++i)
#pragma unroll
            for (int j = 0; j < 4; ++j) s[i][j] = 0.f;
#pragma unroll 4
        for (int d = 0; d < 64; ++d) {
            float a[4], b[4];
            *(float4*)&a[0] = *(const float4*)&QT[d][tr * 4];
            *(float4*)&b[0] = *(const float4*)&KP[d][tc * 4];
#pragma unroll
            for (int i = 0; i < 4; ++i)
#pragma unroll
                for (int j = 0; j < 4; ++j)
                    s[i][j] = fmaf(a[i], b[j], s[i][j]);
        }
        __syncthreads();   // everyone done reading KP as K^T

#pragma unroll
        for (int i = 0; i < 4; ++i)
#pragma unroll
            for (int j = 0; j < 4; ++j) {
                float p = 0.f;
#pragma unroll
                for (int w = 0; w < NWL; ++w)
                    p = fmaf(wreg[i][w], __expf(cl[w] * s[i][j]), p);
                KP[tr * 4 + i][tc * 4 + j] = p;   // P chunk [row][k]
            }
        __syncthreads();

#pragma unroll 4
        for (int k = 0; k < 64; ++k) {
            float vv[4];
            *(float4*)&vv[0] = *(const float4*)&Vs[k][tc * 4];
            float pv[4];
#pragma unroll
            for (int i = 0; i < 4; ++i) pv[i] = KP[tr * 4 + i][k];
#pragma unroll
            for (int i = 0; i < 4; ++i)
#pragma unroll
                for (int j = 0; j < 4; ++j)
                    outA[i][j] = fmaf(pv[i], vv[j], outA[i][j]);
        }
        __syncthreads();
    }

#pragma unroll
    for (int i = 0; i < 4; ++i) {
        const int q = qbase + tr * 4 + i;
        *(float4*)&comb[(size_t)q * 1024 + h * 64 + tc * 4] = *(float4*)&outA[i][0];
    }
}

// ---------------------------------------------------------------------------
extern "C" void kernel_launch(void* const* d_in, const int* in_sizes, int n_in,
                              void* d_out, int out_size, void* d_ws, size_t ws_size,
                              hipStream_t stream)
{
    const float* x  = (const float*)d_in[0];
    const float* Wq = (const float*)d_in[1];
    const float* bq = (const float*)d_in[2];
    const float* Wk = (const float*)d_in[3];
    const float* bk = (const float*)d_in[4];
    const float* Wv = (const float*)d_in[5];
    const float* bv = (const float*)d_in[6];
    const float* Wo = (const float*)d_in[7];
    const float* bo = (const float*)d_in[8];
    const float* pm = (const float*)d_in[9];
    const float* iw = (const float*)d_in[10];
    float* out = (float*)d_out;

    // workspace layout (floats): Q | K | V : 16*1024*64 each, comb: 1024*1024,
    // wgt: 16*1024*16.  Total 4.25M floats = 17 MB.
    float* ws   = (float*)d_ws;
    float* Q    = ws;
    float* K    = ws + (1u << 20);
    float* V    = ws + (2u << 20);
    float* comb = ws + (3u << 20);
    float* wgt  = ws + (4u << 20);

    dim3 blk(256);
    // QKV projections (head-split layout)
    gemm_xw<1><<<dim3(8, 8, 3), blk, 0, stream>>>(x, Wq, Wk, Wv, bq, bk, bv, Q, K, V);
    // softmax denominators -> combined per-(row,wl) weights
    denom_k<<<dim3(16, 16), blk, 0, stream>>>(Q, K, pm, iw, wgt);
    // fused S -> P_sum -> P_sum@V -> comb[s][e]
    pv_k<<<dim3(16, 16), blk, 0, stream>>>(Q, K, V, pm, wgt, comb);
    // output projection
    gemm_xw<0><<<dim3(8, 8, 1), blk, 0, stream>>>(comb, Wo, Wo, Wo, bo, bo, bo, out, out, out);
}

// Round 2
// 252.937 us; speedup vs baseline: 1.7818x; 1.7818x over previous
//
#include <hip/hip_runtime.h>
#include <hip/hip_bf16.h>
#include <math.h>

#define NH 16
#define HD 64
#define NWL 16

typedef __attribute__((ext_vector_type(8))) short short8;
typedef __attribute__((ext_vector_type(8))) unsigned short ushort8;
typedef __attribute__((ext_vector_type(4))) unsigned short ushort4v;
typedef __attribute__((ext_vector_type(4))) float f32x4;

static __device__ __forceinline__ unsigned short f2bf(float f) {
    union { float f; unsigned int u; } v; v.f = f;
    unsigned int r = v.u + 0x7fffu + ((v.u >> 16) & 1u);   // RNE
    return (unsigned short)(r >> 16);
}

// ---------------------------------------------------------------------------
// cast x (fp32 -> bf16), 8 elems/thread
// ---------------------------------------------------------------------------
__global__ __launch_bounds__(256)
void cast_x_k(const float* __restrict__ X, unsigned short* __restrict__ Xb)
{
    const int i = (blockIdx.x * 256 + threadIdx.x) * 8;
    float4 v0 = *(const float4*)&X[i];
    float4 v1 = *(const float4*)&X[i + 4];
    ushort8 o;
    o[0] = f2bf(v0.x); o[1] = f2bf(v0.y); o[2] = f2bf(v0.z); o[3] = f2bf(v0.w);
    o[4] = f2bf(v1.x); o[5] = f2bf(v1.y); o[6] = f2bf(v1.z); o[7] = f2bf(v1.w);
    *(ushort8*)&Xb[i] = o;
}

// ---------------------------------------------------------------------------
// cast + transpose W[e][f] -> WT[f][e] bf16, 64x64 tiles, z picks which W
// ---------------------------------------------------------------------------
__global__ __launch_bounds__(256)
void castT_w(const float* __restrict__ W0, const float* __restrict__ W1,
             const float* __restrict__ W2, const float* __restrict__ W3,
             unsigned short* __restrict__ WT)
{
    const float* W = W0;
    if (blockIdx.z == 1) W = W1;
    if (blockIdx.z == 2) W = W2;
    if (blockIdx.z == 3) W = W3;
    unsigned short* out = WT + ((size_t)blockIdx.z << 20);

    __shared__ float Ts[64][65];
    const int t = threadIdx.x;
    const int ebase = blockIdx.y * 64;
    const int fbase = blockIdx.x * 64;

    {
        const int r0 = (t >> 4) * 4;
        const int c0 = (t & 15) * 4;
#pragma unroll
        for (int r = 0; r < 4; ++r) {
            float4 v = *(const float4*)&W[(size_t)(ebase + r0 + r) * 1024 + fbase + c0];
            Ts[r0 + r][c0 + 0] = v.x;
            Ts[r0 + r][c0 + 1] = v.y;
            Ts[r0 + r][c0 + 2] = v.z;
            Ts[r0 + r][c0 + 3] = v.w;
        }
    }
    __syncthreads();

    const int f = t >> 2;
    const int eseg = (t & 3) * 16;
    unsigned short tmp[16];
#pragma unroll
    for (int j = 0; j < 16; ++j) tmp[j] = f2bf(Ts[eseg + j][f]);
    *(ushort8*)&out[(size_t)(fbase + f) * 1024 + ebase + eseg]     = *(ushort8*)&tmp[0];
    *(ushort8*)&out[(size_t)(fbase + f) * 1024 + ebase + eseg + 8] = *(ushort8*)&tmp[8];
}

// ---------------------------------------------------------------------------
// MFMA GEMM: C[s][f] = sum_e A[s][e]*W[e][f] + bias[f]
//   A bf16 [1024][1024] row-major (k contiguous)
//   Bt bf16 [f][e]      row-major (k contiguous)  — pre-transposed W
// 64x64 block tile, BK=32, 4 waves (2x2), each wave 32x32 via 2x2 frags of
// 16x16x32. Double-buffered LDS, 1 barrier/tile. Rows padded 32->40 bf16
// (80 B) so frag ds_read_b128 lands 2-way max (free).
// MODE 0: out[s*1024+f]   MODE 1: head-split out[h][s][d] (h = blockIdx.x)
// blockIdx.z selects (Bt slab, bias, out) so QKV is one launch.
// ---------------------------------------------------------------------------
template<int MODE>
__global__ __launch_bounds__(256)
void gemm_mfma(const unsigned short* __restrict__ A,
               const unsigned short* __restrict__ BtBase,
               const float* __restrict__ B0, const float* __restrict__ B1,
               const float* __restrict__ B2,
               float* __restrict__ O0, float* __restrict__ O1,
               float* __restrict__ O2)
{
    const int z = blockIdx.z;
    const unsigned short* Bt = BtBase + ((size_t)z << 20);
    const float* bias = B0; float* O = O0;
    if (z == 1) { bias = B1; O = O1; }
    if (z == 2) { bias = B2; O = O2; }

    __shared__ unsigned short As[2][64][40];
    __shared__ unsigned short Bs[2][64][40];

    const int t = threadIdx.x;
    const int lane = t & 63;
    const int w = t >> 6;
    const int w_r = w >> 1;          // 0..1
    const int w_c = w & 1;           // 0..1
    const int sbase = blockIdx.y * 64;
    const int fbase = blockIdx.x * 64;

    const int srow = t >> 2;         // staging row 0..63
    const int skseg = (t & 3) * 8;   // staging k-seg

    f32x4 acc[2][2];
#pragma unroll
    for (int m = 0; m < 2; ++m)
#pragma unroll
        for (int n = 0; n < 2; ++n) acc[m][n] = (f32x4){0.f, 0.f, 0.f, 0.f};

    const int lr = lane & 15;
    const int lk = (lane >> 4) * 8;

    // prologue stage tile 0
    {
        ushort8 av = *(const ushort8*)&A [(size_t)(sbase + srow) * 1024 + skseg];
        ushort8 bv = *(const ushort8*)&Bt[(size_t)(fbase + srow) * 1024 + skseg];
        *(ushort8*)&As[0][srow][skseg] = av;
        *(ushort8*)&Bs[0][srow][skseg] = bv;
    }
    __syncthreads();

    for (int tile = 0; tile < 32; ++tile) {
        const int cur = tile & 1;
        if (tile < 31) {
            const int kb = (tile + 1) * 32;
            ushort8 av = *(const ushort8*)&A [(size_t)(sbase + srow) * 1024 + kb + skseg];
            ushort8 bv = *(const ushort8*)&Bt[(size_t)(fbase + srow) * 1024 + kb + skseg];
            *(ushort8*)&As[cur ^ 1][srow][skseg] = av;
            *(ushort8*)&Bs[cur ^ 1][srow][skseg] = bv;
        }
        short8 a0 = *(const short8*)&As[cur][w_r * 32 + 0  + lr][lk];
        short8 a1 = *(const short8*)&As[cur][w_r * 32 + 16 + lr][lk];
        short8 b0 = *(const short8*)&Bs[cur][w_c * 32 + 0  + lr][lk];
        short8 b1 = *(const short8*)&Bs[cur][w_c * 32 + 16 + lr][lk];
        acc[0][0] = __builtin_amdgcn_mfma_f32_16x16x32_bf16(a0, b0, acc[0][0], 0, 0, 0);
        acc[0][1] = __builtin_amdgcn_mfma_f32_16x16x32_bf16(a0, b1, acc[0][1], 0, 0, 0);
        acc[1][0] = __builtin_amdgcn_mfma_f32_16x16x32_bf16(a1, b0, acc[1][0], 0, 0, 0);
        acc[1][1] = __builtin_amdgcn_mfma_f32_16x16x32_bf16(a1, b1, acc[1][1], 0, 0, 0);
        __syncthreads();
    }

    // epilogue: C row = (lane>>4)*4 + reg, col = lane&15  [m89-verified layout]
#pragma unroll
    for (int m = 0; m < 2; ++m) {
        const int row0 = sbase + w_r * 32 + m * 16 + (lane >> 4) * 4;
#pragma unroll
        for (int n = 0; n < 2; ++n) {
            const int col = fbase + w_c * 32 + n * 16 + (lane & 15);
            const float bval = bias[col];
#pragma unroll
            for (int r = 0; r < 4; ++r) {
                const float val = acc[m][n][r] + bval;
                if (MODE == 0)
                    O[(size_t)(row0 + r) * 1024 + col] = val;
                else
                    O[((size_t)(col >> 6) << 16) + (size_t)(row0 + r) * 64 + (col & 63)] = val;
            }
        }
    }
}

// ---------------------------------------------------------------------------
// Pass 1: per (head, row, wl) softmax denominators -> combined weight
//   wgt[h][q][wl] = iw[wl] / (16 * sum_k exp(c[wl]*S[q][k]))
// ---------------------------------------------------------------------------
__global__ __launch_bounds__(256)
void denom_k(const float* __restrict__ Qb, const float* __restrict__ Kb,
             const float* __restrict__ pm, const float* __restrict__ iw,
             float* __restrict__ wgt)
{
    const int h = blockIdx.y;
    const int qbase = blockIdx.x * 64;
    const int t = threadIdx.x;
    const int tr = t >> 4;
    const int tc = t & 15;

    __shared__ float QT[64][68];
    __shared__ float KT[64][68];
    __shared__ float ccs[16];

    const float* Qh = Qb + ((size_t)h << 16);
    const float* Kh = Kb + ((size_t)h << 16);

    if (t < 16) { float m = cosf(pm[t * NH + h]); ccs[t] = m * m * 0.125f; }
    {
        const int rr = t >> 2;
        const int d0 = (t & 3) * 16;
#pragma unroll
        for (int j = 0; j < 4; ++j) {
            float4 v = *(const float4*)&Qh[(size_t)(qbase + rr) * 64 + d0 + j * 4];
            QT[d0 + j * 4 + 0][rr] = v.x;
            QT[d0 + j * 4 + 1][rr] = v.y;
            QT[d0 + j * 4 + 2][rr] = v.z;
            QT[d0 + j * 4 + 3][rr] = v.w;
        }
    }
    __syncthreads();

    float cl[16];
#pragma unroll
    for (int w = 0; w < NWL; ++w) cl[w] = ccs[w];

    float den[4][16];
#pragma unroll
    for (int i = 0; i < 4; ++i)
#pragma unroll
        for (int w = 0; w < NWL; ++w) den[i][w] = 0.f;

    for (int kb = 0; kb < 1024; kb += 64) {
        {
            const int kk = t >> 2;
            const int d0 = (t & 3) * 16;
#pragma unroll
            for (int j = 0; j < 4; ++j) {
                float4 v = *(const float4*)&Kh[(size_t)(kb + kk) * 64 + d0 + j * 4];
                KT[d0 + j * 4 + 0][kk] = v.x;
                KT[d0 + j * 4 + 1][kk] = v.y;
                KT[d0 + j * 4 + 2][kk] = v.z;
                KT[d0 + j * 4 + 3][kk] = v.w;
            }
        }
        __syncthreads();

        float s[4][4];
#pragma unroll
        for (int i = 0; i < 4; ++i)
#pragma unroll
            for (int j = 0; j < 4; ++j) s[i][j] = 0.f;
#pragma unroll 4
        for (int d = 0; d < 64; ++d) {
            float a[4], b[4];
            *(float4*)&a[0] = *(const float4*)&QT[d][tr * 4];
            *(float4*)&b[0] = *(const float4*)&KT[d][tc * 4];
#pragma unroll
            for (int i = 0; i < 4; ++i)
#pragma unroll
                for (int j = 0; j < 4; ++j)
                    s[i][j] = fmaf(a[i], b[j], s[i][j]);
        }
#pragma unroll
        for (int i = 0; i < 4; ++i)
#pragma unroll
            for (int j = 0; j < 4; ++j)
#pragma unroll
                for (int w = 0; w < NWL; ++w)
                    den[i][w] += __expf(cl[w] * s[i][j]);
        __syncthreads();
    }

#pragma unroll
    for (int off = 1; off < 16; off <<= 1)
#pragma unroll
        for (int i = 0; i < 4; ++i)
#pragma unroll
            for (int w = 0; w < NWL; ++w)
                den[i][w] += __shfl_xor(den[i][w], off, 64);

    if (tc == 0) {
#pragma unroll
        for (int i = 0; i < 4; ++i) {
            const int q = qbase + tr * 4 + i;
#pragma unroll
            for (int w = 0; w < NWL; ++w)
                wgt[(((size_t)h << 10) + q) * NWL + w] = iw[w] / (den[i][w] * 16.0f);
        }
    }
}

// ---------------------------------------------------------------------------
// Pass 2: fused S -> P_sum -> P_sum @ V, writes comb (bf16) [s][h*64+d]
// ---------------------------------------------------------------------------
__global__ __launch_bounds__(256)
void pv_k(const float* __restrict__ Qb, const float* __restrict__ Kb,
          const float* __restrict__ Vb, const float* __restrict__ pm,
          const float* __restrict__ wgt, unsigned short* __restrict__ comb)
{
    const int h = blockIdx.y;
    const int qbase = blockIdx.x * 64;
    const int t = threadIdx.x;
    const int tr = t >> 4;
    const int tc = t & 15;

    __shared__ float QT[64][68];
    __shared__ float KP[64][68];
    __shared__ float Vs[64][68];
    __shared__ float ccs[16];

    const float* Qh = Qb + ((size_t)h << 16);
    const float* Kh = Kb + ((size_t)h << 16);
    const float* Vh = Vb + ((size_t)h << 16);

    if (t < 16) { float m = cosf(pm[t * NH + h]); ccs[t] = m * m * 0.125f; }
    {
        const int rr = t >> 2;
        const int d0 = (t & 3) * 16;
#pragma unroll
        for (int j = 0; j < 4; ++j) {
            float4 v = *(const float4*)&Qh[(size_t)(qbase + rr) * 64 + d0 + j * 4];
            QT[d0 + j * 4 + 0][rr] = v.x;
            QT[d0 + j * 4 + 1][rr] = v.y;
            QT[d0 + j * 4 + 2][rr] = v.z;
            QT[d0 + j * 4 + 3][rr] = v.w;
        }
    }
    __syncthreads();

    float cl[16];
#pragma unroll
    for (int w = 0; w < NWL; ++w) cl[w] = ccs[w];

    float wreg[4][16];
#pragma unroll
    for (int i = 0; i < 4; ++i) {
        const int q = qbase + tr * 4 + i;
#pragma unroll
        for (int w = 0; w < NWL; ++w)
            wreg[i][w] = wgt[(((size_t)h << 10) + q) * NWL + w];
    }

    float outA[4][4];
#pragma unroll
    for (int i = 0; i < 4; ++i)
#pragma unroll
        for (int j = 0; j < 4; ++j) outA[i][j] = 0.f;

    for (int kb = 0; kb < 1024; kb += 64) {
        {
            const int kk = t >> 2;
            const int d0 = (t & 3) * 16;
#pragma unroll
            for (int j = 0; j < 4; ++j) {
                float4 v = *(const float4*)&Kh[(size_t)(kb + kk) * 64 + d0 + j * 4];
                KP[d0 + j * 4 + 0][kk] = v.x;
                KP[d0 + j * 4 + 1][kk] = v.y;
                KP[d0 + j * 4 + 2][kk] = v.z;
                KP[d0 + j * 4 + 3][kk] = v.w;
                *(float4*)&Vs[kk][d0 + j * 4] =
                    *(const float4*)&Vh[(size_t)(kb + kk) * 64 + d0 + j * 4];
            }
        }
        __syncthreads();

        float s[4][4];
#pragma unroll
        for (int i = 0; i < 4; ++i)
#pragma unroll
            for (int j = 0; j < 4; ++j) s[i][j] = 0.f;
#pragma unroll 4
        for (int d = 0; d < 64; ++d) {
            float a[4], b[4];
            *(float4*)&a[0] = *(const float4*)&QT[d][tr * 4];
            *(float4*)&b[0] = *(const float4*)&KP[d][tc * 4];
#pragma unroll
            for (int i = 0; i < 4; ++i)
#pragma unroll
                for (int j = 0; j < 4; ++j)
                    s[i][j] = fmaf(a[i], b[j], s[i][j]);
        }
        __syncthreads();

#pragma unroll
        for (int i = 0; i < 4; ++i)
#pragma unroll
            for (int j = 0; j < 4; ++j) {
                float p = 0.f;
#pragma unroll
                for (int w = 0; w < NWL; ++w)
                    p = fmaf(wreg[i][w], __expf(cl[w] * s[i][j]), p);
                KP[tr * 4 + i][tc * 4 + j] = p;
            }
        __syncthreads();

#pragma unroll 4
        for (int k = 0; k < 64; ++k) {
            float vv[4];
            *(float4*)&vv[0] = *(const float4*)&Vs[k][tc * 4];
            float pv[4];
#pragma unroll
            for (int i = 0; i < 4; ++i) pv[i] = KP[tr * 4 + i][k];
#pragma unroll
            for (int i = 0; i < 4; ++i)
#pragma unroll
                for (int j = 0; j < 4; ++j)
                    outA[i][j] = fmaf(pv[i], vv[j], outA[i][j]);
        }
        __syncthreads();
    }

#pragma unroll
    for (int i = 0; i < 4; ++i) {
        const int q = qbase + tr * 4 + i;
        ushort4v o;
        o[0] = f2bf(outA[i][0]);
        o[1] = f2bf(outA[i][1]);
        o[2] = f2bf(outA[i][2]);
        o[3] = f2bf(outA[i][3]);
        *(ushort4v*)&comb[(size_t)q * 1024 + h * 64 + tc * 4] = o;
    }
}

// ---------------------------------------------------------------------------
extern "C" void kernel_launch(void* const* d_in, const int* in_sizes, int n_in,
                              void* d_out, int out_size, void* d_ws, size_t ws_size,
                              hipStream_t stream)
{
    const float* x  = (const float*)d_in[0];
    const float* Wq = (const float*)d_in[1];
    const float* bq = (const float*)d_in[2];
    const float* Wk = (const float*)d_in[3];
    const float* bk = (const float*)d_in[4];
    const float* Wv = (const float*)d_in[5];
    const float* bv = (const float*)d_in[6];
    const float* Wo = (const float*)d_in[7];
    const float* bo = (const float*)d_in[8];
    const float* pm = (const float*)d_in[9];
    const float* iw = (const float*)d_in[10];
    float* out = (float*)d_out;

    // ws layout: Xb (1M u16, reused later as comb bf16) | WT (4M u16) |
    //            Q | K | V (1M f32 each) | wgt (256K f32)   => ~23 MB
    unsigned short* Xb = (unsigned short*)d_ws;
    unsigned short* WT = Xb + (1u << 20);
    float* Q   = (float*)(WT + (4u << 20));
    float* K   = Q + (1u << 20);
    float* V   = K + (1u << 20);
    float* wgt = V + (1u << 20);
    unsigned short* combB = Xb;   // reuse: Xb dead after QKV GEMM

    dim3 blk(256);
    cast_x_k<<<dim3(512), blk, 0, stream>>>(x, Xb);
    castT_w<<<dim3(16, 16, 4), blk, 0, stream>>>(Wq, Wk, Wv, Wo, WT);
    // QKV projections (bf16 MFMA, head-split fp32 out)
    gemm_mfma<1><<<dim3(16, 16, 3), blk, 0, stream>>>(Xb, WT, bq, bk, bv, Q, K, V);
    // softmax denominators
    denom_k<<<dim3(16, 16), blk, 0, stream>>>(Q, K, pm, iw, wgt);
    // fused S -> P_sum -> PV -> comb (bf16)
    pv_k<<<dim3(16, 16), blk, 0, stream>>>(Q, K, V, pm, wgt, combB);
    // output projection: comb_bf16 @ Wo + bo -> out (WT slab 3)
    gemm_mfma<0><<<dim3(16, 16, 1), blk, 0, stream>>>(
        combB, WT + (3u << 20), bo, bo, bo, out, out, out);
}

// Round 3
// 197.651 us; speedup vs baseline: 2.2801x; 1.2797x over previous
//
#include <hip/hip_runtime.h>
#include <hip/hip_fp16.h>
#include <math.h>

#define NH 16
#define NWL 16

typedef _Float16 half8 __attribute__((ext_vector_type(8)));
typedef _Float16 half4 __attribute__((ext_vector_type(4)));
typedef float f32x4 __attribute__((ext_vector_type(4)));

// ---------------------------------------------------------------------------
// cast x (fp32 -> f16), 8 elems/thread
// ---------------------------------------------------------------------------
__global__ __launch_bounds__(256)
void cast_x_k(const float* __restrict__ X, _Float16* __restrict__ Xh)
{
    const int i = (blockIdx.x * 256 + threadIdx.x) * 8;
    float4 v0 = *(const float4*)&X[i];
    float4 v1 = *(const float4*)&X[i + 4];
    half8 o;
    o[0] = (_Float16)v0.x; o[1] = (_Float16)v0.y; o[2] = (_Float16)v0.z; o[3] = (_Float16)v0.w;
    o[4] = (_Float16)v1.x; o[5] = (_Float16)v1.y; o[6] = (_Float16)v1.z; o[7] = (_Float16)v1.w;
    *(half8*)&Xh[i] = o;
}

// ---------------------------------------------------------------------------
// cast + transpose W[e][f] -> WT[f][e] f16, 64x64 tiles, z picks which W
// ---------------------------------------------------------------------------
__global__ __launch_bounds__(256)
void castT_w(const float* __restrict__ W0, const float* __restrict__ W1,
             const float* __restrict__ W2, const float* __restrict__ W3,
             _Float16* __restrict__ WT)
{
    const float* W = W0;
    if (blockIdx.z == 1) W = W1;
    if (blockIdx.z == 2) W = W2;
    if (blockIdx.z == 3) W = W3;
    _Float16* out = WT + ((size_t)blockIdx.z << 20);

    __shared__ float Ts[64][65];
    const int t = threadIdx.x;
    const int ebase = blockIdx.y * 64;
    const int fbase = blockIdx.x * 64;

    {
        const int r0 = (t >> 4) * 4;
        const int c0 = (t & 15) * 4;
#pragma unroll
        for (int r = 0; r < 4; ++r) {
            float4 v = *(const float4*)&W[(size_t)(ebase + r0 + r) * 1024 + fbase + c0];
            Ts[r0 + r][c0 + 0] = v.x;
            Ts[r0 + r][c0 + 1] = v.y;
            Ts[r0 + r][c0 + 2] = v.z;
            Ts[r0 + r][c0 + 3] = v.w;
        }
    }
    __syncthreads();

    const int f = t >> 2;
    const int eseg = (t & 3) * 16;
    half8 lo, hi;
#pragma unroll
    for (int j = 0; j < 8; ++j) lo[j] = (_Float16)Ts[eseg + j][f];
#pragma unroll
    for (int j = 0; j < 8; ++j) hi[j] = (_Float16)Ts[eseg + 8 + j][f];
    *(half8*)&out[(size_t)(fbase + f) * 1024 + ebase + eseg]     = lo;
    *(half8*)&out[(size_t)(fbase + f) * 1024 + ebase + eseg + 8] = hi;
}

// ---------------------------------------------------------------------------
// MFMA GEMM (f16): C[s][f] = sum_e A[s][e]*W[e][f] + bias[f]
// 64x64 tile, BK=32, 4 waves (2x2), 16x16x32_f16 frags, double-buffered LDS.
// MODE 0: fp32 out[s][f]
// MODE 1: f16 head-split: z=0,1 -> O[h][s][d]; z=2 -> transposed O[h][d][s]
// ---------------------------------------------------------------------------
template<int MODE>
__global__ __launch_bounds__(256)
void gemm_mfma(const _Float16* __restrict__ A,
               const _Float16* __restrict__ BtBase,
               const float* __restrict__ B0, const float* __restrict__ B1,
               const float* __restrict__ B2,
               void* __restrict__ O0p, void* __restrict__ O1p, void* __restrict__ O2p)
{
    const int z = blockIdx.z;
    const _Float16* Bt = BtBase + ((size_t)z << 20);
    const float* bias = B0; void* Op = O0p;
    if (z == 1) { bias = B1; Op = O1p; }
    if (z == 2) { bias = B2; Op = O2p; }

    __shared__ _Float16 As[2][64][40];
    __shared__ _Float16 Bs[2][64][40];

    const int t = threadIdx.x;
    const int lane = t & 63;
    const int w = t >> 6;
    const int w_r = w >> 1;
    const int w_c = w & 1;
    const int sbase = blockIdx.y * 64;
    const int fbase = blockIdx.x * 64;

    const int srow = t >> 2;
    const int skseg = (t & 3) * 8;

    f32x4 acc[2][2];
#pragma unroll
    for (int m = 0; m < 2; ++m)
#pragma unroll
        for (int n = 0; n < 2; ++n) acc[m][n] = (f32x4){0.f, 0.f, 0.f, 0.f};

    const int lr = lane & 15;
    const int lk = (lane >> 4) * 8;

    {
        *(half8*)&As[0][srow][skseg] = *(const half8*)&A [(size_t)(sbase + srow) * 1024 + skseg];
        *(half8*)&Bs[0][srow][skseg] = *(const half8*)&Bt[(size_t)(fbase + srow) * 1024 + skseg];
    }
    __syncthreads();

    for (int tile = 0; tile < 32; ++tile) {
        const int cur = tile & 1;
        if (tile < 31) {
            const int kb = (tile + 1) * 32;
            half8 av = *(const half8*)&A [(size_t)(sbase + srow) * 1024 + kb + skseg];
            half8 bv = *(const half8*)&Bt[(size_t)(fbase + srow) * 1024 + kb + skseg];
            *(half8*)&As[cur ^ 1][srow][skseg] = av;
            *(half8*)&Bs[cur ^ 1][srow][skseg] = bv;
        }
        half8 a0 = *(const half8*)&As[cur][w_r * 32 + 0  + lr][lk];
        half8 a1 = *(const half8*)&As[cur][w_r * 32 + 16 + lr][lk];
        half8 b0 = *(const half8*)&Bs[cur][w_c * 32 + 0  + lr][lk];
        half8 b1 = *(const half8*)&Bs[cur][w_c * 32 + 16 + lr][lk];
        acc[0][0] = __builtin_amdgcn_mfma_f32_16x16x32_f16(a0, b0, acc[0][0], 0, 0, 0);
        acc[0][1] = __builtin_amdgcn_mfma_f32_16x16x32_f16(a0, b1, acc[0][1], 0, 0, 0);
        acc[1][0] = __builtin_amdgcn_mfma_f32_16x16x32_f16(a1, b0, acc[1][0], 0, 0, 0);
        acc[1][1] = __builtin_amdgcn_mfma_f32_16x16x32_f16(a1, b1, acc[1][1], 0, 0, 0);
        __syncthreads();
    }

#pragma unroll
    for (int m = 0; m < 2; ++m) {
        const int row0 = sbase + w_r * 32 + m * 16 + (lane >> 4) * 4;
#pragma unroll
        for (int n = 0; n < 2; ++n) {
            const int col = fbase + w_c * 32 + n * 16 + (lane & 15);
            const float bval = bias[col];
            if (MODE == 0) {
                float* O = (float*)Op;
#pragma unroll
                for (int r = 0; r < 4; ++r)
                    O[(size_t)(row0 + r) * 1024 + col] = acc[m][n][r] + bval;
            } else {
                _Float16* O = (_Float16*)Op;
                const int hh = col >> 6;
                const int d = col & 63;
                if (z == 2) {   // V transposed: O[h][d][s]
                    half4 o;
#pragma unroll
                    for (int r = 0; r < 4; ++r) o[r] = (_Float16)(acc[m][n][r] + bval);
                    *(half4*)&O[((size_t)hh << 16) + (size_t)d * 1024 + row0] = o;
                } else {        // Q/K: O[h][s][d]
#pragma unroll
                    for (int r = 0; r < 4; ++r)
                        O[((size_t)hh << 16) + (size_t)(row0 + r) * 64 + d] =
                            (_Float16)(acc[m][n][r] + bval);
                }
            }
        }
    }
}

// ---------------------------------------------------------------------------
// Fused attention: per (head, 64-q block):
//  Phase A: S = K·Q^T via MFMA, accumulate per-(q,wl) exp2 denominators
//  Phase B: recompute S, P = sum_wl wgt*exp2(c*s) -> f16, PV via MFMA
// Wave w owns q rows [w*16, w*16+16). exp-dominated (~27 us total floor).
// ---------------------------------------------------------------------------
__global__ __launch_bounds__(256)
void attn_k(const _Float16* __restrict__ Qg, const _Float16* __restrict__ Kg,
            const _Float16* __restrict__ Vg, const float* __restrict__ pm,
            const float* __restrict__ iwp, _Float16* __restrict__ comb)
{
    const int h  = blockIdx.y;
    const int qb = blockIdx.x;
    const int t = threadIdx.x;
    const int lane = t & 63;
    const int w = t >> 6;
    const int lr = lane & 15;
    const int lg = lane >> 4;

    __shared__ _Float16 Ks[2][64][72];
    __shared__ _Float16 Vs[2][64][72];
    __shared__ _Float16 Ps[4][16][72];
    __shared__ float sc[16], siw[16];

    if (t < 16) {
        float m = cosf(pm[t * NH + h]);
        sc[t] = m * m * 0.125f * 1.44269504f;   // c * log2(e)
        siw[t] = iwp[t];
    }

    // Q fragments (also valid as B-operand layout)
    const _Float16* Qrow = Qg + ((size_t)h << 16) + (size_t)(qb * 64 + w * 16 + lr) * 64;
    half8 q0 = *(const half8*)&Qrow[lg * 8];
    half8 q1 = *(const half8*)&Qrow[32 + lg * 8];
    __syncthreads();

    float c2[16];
#pragma unroll
    for (int i = 0; i < NWL; ++i) c2[i] = sc[i];

    const _Float16* Kh = Kg + ((size_t)h << 16);
    const _Float16* Vh = Vg + ((size_t)h << 16);

    const int sr = t >> 3;              // staging rows: idx>>3
    const int sg = (t & 7) * 8;

    // ---- Phase A: denominators ----
    float den[16];
#pragma unroll
    for (int i = 0; i < NWL; ++i) den[i] = 0.f;

    {
        *(half8*)&Ks[0][sr][sg]      = *(const half8*)&Kh[(size_t)sr * 64 + sg];
        *(half8*)&Ks[0][sr + 32][sg] = *(const half8*)&Kh[(size_t)(sr + 32) * 64 + sg];
    }
    __syncthreads();

    for (int it = 0; it < 16; ++it) {
        const int buf = it & 1;
        if (it < 15) {
            const int kb = (it + 1) * 64;
            half8 v0 = *(const half8*)&Kh[(size_t)(kb + sr) * 64 + sg];
            half8 v1 = *(const half8*)&Kh[(size_t)(kb + sr + 32) * 64 + sg];
            *(half8*)&Ks[buf ^ 1][sr][sg]      = v0;
            *(half8*)&Ks[buf ^ 1][sr + 32][sg] = v1;
        }
#pragma unroll
        for (int kf = 0; kf < 4; ++kf) {
            half8 a0 = *(const half8*)&Ks[buf][kf * 16 + lr][lg * 8];
            half8 a1 = *(const half8*)&Ks[buf][kf * 16 + lr][32 + lg * 8];
            f32x4 s2 = (f32x4){0.f, 0.f, 0.f, 0.f};
            s2 = __builtin_amdgcn_mfma_f32_16x16x32_f16(a0, q0, s2, 0, 0, 0);
            s2 = __builtin_amdgcn_mfma_f32_16x16x32_f16(a1, q1, s2, 0, 0, 0);
#pragma unroll
            for (int r = 0; r < 4; ++r) {
                const float sv = s2[r];
#pragma unroll
                for (int i = 0; i < NWL; ++i)
                    den[i] += exp2f(c2[i] * sv);
            }
        }
        __syncthreads();
    }

    // reduce over the 4 k-owning lane groups (lane bits 4,5)
#pragma unroll
    for (int off = 16; off < 64; off <<= 1)
#pragma unroll
        for (int i = 0; i < NWL; ++i)
            den[i] += __shfl_xor(den[i], off);

    float wgt[16];
#pragma unroll
    for (int i = 0; i < NWL; ++i) wgt[i] = siw[i] / (den[i] * 16.0f);

    // ---- Phase B: P_sum and PV ----
    f32x4 oacc[4];
#pragma unroll
    for (int n = 0; n < 4; ++n) oacc[n] = (f32x4){0.f, 0.f, 0.f, 0.f};

    {
        *(half8*)&Ks[0][sr][sg]      = *(const half8*)&Kh[(size_t)sr * 64 + sg];
        *(half8*)&Ks[0][sr + 32][sg] = *(const half8*)&Kh[(size_t)(sr + 32) * 64 + sg];
        *(half8*)&Vs[0][sr][sg]      = *(const half8*)&Vh[(size_t)sr * 1024 + sg];
        *(half8*)&Vs[0][sr + 32][sg] = *(const half8*)&Vh[(size_t)(sr + 32) * 1024 + sg];
    }
    __syncthreads();

    for (int it = 0; it < 16; ++it) {
        const int buf = it & 1;
        if (it < 15) {
            const int kb = (it + 1) * 64;
            half8 k0 = *(const half8*)&Kh[(size_t)(kb + sr) * 64 + sg];
            half8 k1 = *(const half8*)&Kh[(size_t)(kb + sr + 32) * 64 + sg];
            half8 v0 = *(const half8*)&Vh[(size_t)sr * 1024 + kb + sg];
            half8 v1 = *(const half8*)&Vh[(size_t)(sr + 32) * 1024 + kb + sg];
            *(half8*)&Ks[buf ^ 1][sr][sg]      = k0;
            *(half8*)&Ks[buf ^ 1][sr + 32][sg] = k1;
            *(half8*)&Vs[buf ^ 1][sr][sg]      = v0;
            *(half8*)&Vs[buf ^ 1][sr + 32][sg] = v1;
        }
#pragma unroll
        for (int kf = 0; kf < 4; ++kf) {
            half8 a0 = *(const half8*)&Ks[buf][kf * 16 + lr][lg * 8];
            half8 a1 = *(const half8*)&Ks[buf][kf * 16 + lr][32 + lg * 8];
            f32x4 s2 = (f32x4){0.f, 0.f, 0.f, 0.f};
            s2 = __builtin_amdgcn_mfma_f32_16x16x32_f16(a0, q0, s2, 0, 0, 0);
            s2 = __builtin_amdgcn_mfma_f32_16x16x32_f16(a1, q1, s2, 0, 0, 0);
            half4 ph;
#pragma unroll
            for (int r = 0; r < 4; ++r) {
                const float sv = s2[r];
                float p = 0.f;
#pragma unroll
                for (int i = 0; i < NWL; ++i)
                    p = fmaf(wgt[i], exp2f(c2[i] * sv), p);
                ph[r] = (_Float16)p;
            }
            *(half4*)&Ps[w][lr][kf * 16 + lg * 4] = ph;   // per-wave private
        }
        // same-wave LDS dependency; compiler inserts lgkm waits
        half8 pa0 = *(const half8*)&Ps[w][lr][lg * 8];
        half8 pa1 = *(const half8*)&Ps[w][lr][32 + lg * 8];
#pragma unroll
        for (int n = 0; n < 4; ++n) {
            half8 vb0 = *(const half8*)&Vs[buf][n * 16 + lr][lg * 8];
            half8 vb1 = *(const half8*)&Vs[buf][n * 16 + lr][32 + lg * 8];
            oacc[n] = __builtin_amdgcn_mfma_f32_16x16x32_f16(pa0, vb0, oacc[n], 0, 0, 0);
            oacc[n] = __builtin_amdgcn_mfma_f32_16x16x32_f16(pa1, vb1, oacc[n], 0, 0, 0);
        }
        __syncthreads();
    }

    // epilogue: lane holds out[q = lg*4+r][d = n*16+lr]
#pragma unroll
    for (int n = 0; n < 4; ++n)
#pragma unroll
        for (int r = 0; r < 4; ++r)
            comb[(size_t)(qb * 64 + w * 16 + lg * 4 + r) * 1024 + h * 64 + n * 16 + lr] =
                (_Float16)oacc[n][r];
}

// ---------------------------------------------------------------------------
extern "C" void kernel_launch(void* const* d_in, const int* in_sizes, int n_in,
                              void* d_out, int out_size, void* d_ws, size_t ws_size,
                              hipStream_t stream)
{
    const float* x  = (const float*)d_in[0];
    const float* Wq = (const float*)d_in[1];
    const float* bq = (const float*)d_in[2];
    const float* Wk = (const float*)d_in[3];
    const float* bk = (const float*)d_in[4];
    const float* Wv = (const float*)d_in[5];
    const float* bv = (const float*)d_in[6];
    const float* Wo = (const float*)d_in[7];
    const float* bo = (const float*)d_in[8];
    const float* pm = (const float*)d_in[9];
    const float* iw = (const float*)d_in[10];
    float* out = (float*)d_out;

    // ws (f16 elems): Xh 1M (reused as comb) | WT 4M | Q 1M | K 1M | Vt 1M = 16 MB
    _Float16* Xh = (_Float16*)d_ws;
    _Float16* WT = Xh + (1u << 20);
    _Float16* Qh = WT + (4u << 20);
    _Float16* Kh = Qh + (1u << 20);
    _Float16* Vt = Kh + (1u << 20);
    _Float16* comb = Xh;   // Xh dead after QKV GEMM

    dim3 blk(256);
    cast_x_k<<<dim3(512), blk, 0, stream>>>(x, Xh);
    castT_w<<<dim3(16, 16, 4), blk, 0, stream>>>(Wq, Wk, Wv, Wo, WT);
    gemm_mfma<1><<<dim3(16, 16, 3), blk, 0, stream>>>(Xh, WT, bq, bk, bv, Qh, Kh, Vt);
    attn_k<<<dim3(16, 16), blk, 0, stream>>>(Qh, Kh, Vt, pm, iw, comb);
    gemm_mfma<0><<<dim3(16, 16, 1), blk, 0, stream>>>(
        comb, WT + (3u << 20), bo, bo, bo, out, out, out);
}